// Round 9
// baseline (230.876 us; speedup 1.0000x reference)
//
#include <hip/hip_runtime.h>

// LIF scan over T=8, N=4.2M float4-sites. Round-8 finding: NT loads+stores
// (bypass MALL allocation) dropped the kernel below the harness's own 80us
// fill dispatches — the rounds-1..7 2.3 TB/s wall was MALL forced-writebacks
// from the harness's 262 MiB dirty restore/poison, invisible to TCC counters.
// Fill kernel proves 6.7 TB/s achievable -> 268 MB traffic floor ~40 us.
// This round: keep NT both ways, add a 2nd independent recurrence chain per
// thread (striped) so each wave holds 2 NT loads in flight (NT always misses
// L3 -> full HBM latency; 1-deep/wave was marginally under the latency-BW
// product at 6.7 TB/s). Grid 2048 blocks = 8 blocks/CU = full wave capacity.

typedef float v4f __attribute__((ext_vector_type(4)));

#define DECAY  0.25f
#define THRESH 0.5f

__global__ __launch_bounds__(256) void lif_scan_kernel(
    const v4f* __restrict__ x, v4f* __restrict__ out,
    int n4, int nthreads) {
    const int tid = blockIdx.x * blockDim.x + threadIdx.x;
    if (tid >= nthreads) return;

    const size_t iA = (size_t)tid;                    // chain A site
    const size_t iB = iA + (size_t)nthreads;          // chain B site (striped)
    const size_t st = (size_t)n4;                     // float4s per t-plane

    v4f mA = {0.f, 0.f, 0.f, 0.f}, sA = mA;
    v4f mB = mA, sB = mA;

#pragma unroll
    for (int t = 0; t < 8; ++t) {
        const size_t off = (size_t)t * st;
        // Two independent NT loads -> 2 in flight per thread.
        const v4f xa = __builtin_nontemporal_load(&x[off + iA]);
        const v4f xb = __builtin_nontemporal_load(&x[off + iB]);

        mA[0] = mA[0] * (DECAY * (1.f - sA[0])) + xa[0];
        mA[1] = mA[1] * (DECAY * (1.f - sA[1])) + xa[1];
        mA[2] = mA[2] * (DECAY * (1.f - sA[2])) + xa[2];
        mA[3] = mA[3] * (DECAY * (1.f - sA[3])) + xa[3];
        sA[0] = (mA[0] >= THRESH) ? 1.f : 0.f;
        sA[1] = (mA[1] >= THRESH) ? 1.f : 0.f;
        sA[2] = (mA[2] >= THRESH) ? 1.f : 0.f;
        sA[3] = (mA[3] >= THRESH) ? 1.f : 0.f;

        mB[0] = mB[0] * (DECAY * (1.f - sB[0])) + xb[0];
        mB[1] = mB[1] * (DECAY * (1.f - sB[1])) + xb[1];
        mB[2] = mB[2] * (DECAY * (1.f - sB[2])) + xb[2];
        mB[3] = mB[3] * (DECAY * (1.f - sB[3])) + xb[3];
        sB[0] = (mB[0] >= THRESH) ? 1.f : 0.f;
        sB[1] = (mB[1] >= THRESH) ? 1.f : 0.f;
        sB[2] = (mB[2] >= THRESH) ? 1.f : 0.f;
        sB[3] = (mB[3] >= THRESH) ? 1.f : 0.f;

        __builtin_nontemporal_store(sA, &out[off + iA]);
        __builtin_nontemporal_store(sB, &out[off + iB]);
    }
}

extern "C" void kernel_launch(void* const* d_in, const int* in_sizes, int n_in,
                              void* d_out, int out_size, void* d_ws, size_t ws_size,
                              hipStream_t stream) {
    const float* x = (const float*)d_in[0];
    float* out = (float*)d_out;

    const int total = in_sizes[0];        // 8 * 32 * 128 * 32 * 32 = 33,554,432
    const int T = 8;
    const int n = total / T;              // 4,194,304 sites per timestep
    const int n4 = n / 4;                 // 1,048,576 float4 groups
    const int nthreads = n4 / 2;          // 524,288 threads, 2 chains each

    const int block = 256;
    const int grid = nthreads / block;    // 2048 blocks

    lif_scan_kernel<<<grid, block, 0, stream>>>(
        (const v4f*)x, (v4f*)out, n4, nthreads);
}